// Round 5
// baseline (378.918 us; speedup 1.0000x reference)
//
#include <hip/hip_runtime.h>
#include <cstdint>
#include <cstddef>

// Static problem geometry
#define LEN_IN  21760
#define BATCH   2
#define MROWS   (BATCH * LEN_IN)   // 43520 = 128 * 340
// Levels: (128,128),(64,64),(32,32),(16,16); starts 0,16384,20480,21504

typedef short    sv8 __attribute__((ext_vector_type(8)));   // 8 bf16
typedef _Float16 hv8 __attribute__((ext_vector_type(8)));   // 8 f16
typedef float    fv4 __attribute__((ext_vector_type(4)));

__device__ __forceinline__ unsigned short f2bf(float f) {
  unsigned u = __float_as_uint(f);
  u += 0x7fff + ((u >> 16) & 1);           // RNE
  return (unsigned short)(u >> 16);
}
__device__ __forceinline__ float bf2f(unsigned short s) {
  return __uint_as_float(((unsigned)s) << 16);
}

// ---------------------------------------------------------------------------
// Weight prep (1 launch): transpose K-major -> [N][K].
// Wv, Wa, Wo -> f16; Woff -> split-bf16 (hi,lo).
// ---------------------------------------------------------------------------
__global__ __launch_bounds__(256) void cvt_weights(
    const float* __restrict__ Wv, const float* __restrict__ Woff,
    const float* __restrict__ Wa, const float* __restrict__ Wo,
    _Float16* __restrict__ WvT, short* __restrict__ WoffTh, short* __restrict__ WoffTl,
    _Float16* __restrict__ WaT, _Float16* __restrict__ WoT)
{
  const int b = blockIdx.x, k = threadIdx.x;
  if (b < 256) {
    WvT[(size_t)b * 256 + k] = (_Float16)Wv[(size_t)k * 256 + b];
  } else if (b < 512) {
    const int n = b - 256;
    const float v = Woff[(size_t)k * 256 + n];
    const unsigned short h = f2bf(v);
    WoffTh[(size_t)n * 256 + k] = h;
    WoffTl[(size_t)n * 256 + k] = f2bf(v - bf2f(h));
  } else if (b < 640) {
    const int n = b - 512;
    WaT[(size_t)n * 256 + k] = (_Float16)Wa[(size_t)k * 128 + n];
  } else {
    const int n = b - 640;
    WoT[(size_t)n * 256 + k] = (_Float16)Wo[(size_t)k * 256 + n];
  }
}

// ---------------------------------------------------------------------------
// Barrier-free direct-from-global f16 MFMA GEMM.
// C[M,TN] = A[M,256] @ Bt[TN,256]^T + bias.  Block 128 x TN, 4 waves (2x2),
// wave tile 64 x TN/2.  A frags loaded straight to VGPRs (register double-
// buffered); B frags from L2/L3.  No LDS, no __syncthreads.
// AF32: A is fp32 (convert in regs) else f16.  OUTF16: f16 store else fp32.
// ---------------------------------------------------------------------------
template<int TN, int AF32, int OUTF16>
__global__ __launch_bounds__(256, 2) void gemm_f16d(
    const void* __restrict__ Ap, const _Float16* __restrict__ Bt,
    const float* __restrict__ bias, void* __restrict__ Cout)
{
  constexpr int JF = TN / 32;
  const int tid = threadIdx.x, lane = tid & 63, wave = tid >> 6;
  const int l15 = lane & 15, quad = lane >> 4;
  const int wr = (wave & 1) * 64, wc = (wave >> 1) * (TN / 2);
  const int rowA = blockIdx.x * 128 + wr + l15;
  const int kq = quad * 8;

  hv8 a_pf[4];
  auto loadA = [&](int kk, hv8* dst) {
    if constexpr (AF32) {
      const float* A = (const float*)Ap;
#pragma unroll
      for (int i = 0; i < 4; ++i) {
        const float4 f0 = *(const float4*)&A[(size_t)(rowA + i * 16) * 256 + kk];
        const float4 f1 = *(const float4*)&A[(size_t)(rowA + i * 16) * 256 + kk + 4];
        hv8 h;
        h[0] = (_Float16)f0.x; h[1] = (_Float16)f0.y; h[2] = (_Float16)f0.z; h[3] = (_Float16)f0.w;
        h[4] = (_Float16)f1.x; h[5] = (_Float16)f1.y; h[6] = (_Float16)f1.z; h[7] = (_Float16)f1.w;
        dst[i] = h;
      }
    } else {
      const _Float16* A = (const _Float16*)Ap;
#pragma unroll
      for (int i = 0; i < 4; ++i)
        dst[i] = *(const hv8*)&A[(size_t)(rowA + i * 16) * 256 + kk];
    }
  };

  loadA(kq, a_pf);
  fv4 acc[4][JF] = {};

  for (int k0 = 0; k0 < 256; k0 += 32) {
    hv8 a[4];
#pragma unroll
    for (int i = 0; i < 4; ++i) a[i] = a_pf[i];
    if (k0 < 224) loadA(k0 + 32 + kq, a_pf);
#pragma unroll
    for (int j = 0; j < JF; ++j) {
      const hv8 b = *(const hv8*)&Bt[(size_t)(wc + j * 16 + l15) * 256 + k0 + kq];
#pragma unroll
      for (int i = 0; i < 4; ++i)
        acc[i][j] = __builtin_amdgcn_mfma_f32_16x16x32_f16(a[i], b, acc[i][j], 0, 0, 0);
    }
  }

#pragma unroll
  for (int j = 0; j < JF; ++j) {
    const int col = wc + j * 16 + l15;
    const float bj = bias[col];
#pragma unroll
    for (int i = 0; i < 4; ++i)
#pragma unroll
      for (int rg = 0; rg < 4; ++rg) {
        const int row = blockIdx.x * 128 + wr + i * 16 + quad * 4 + rg;
        const float v = acc[i][j][rg] + bj;
        if (OUTF16) ((_Float16*)Cout)[(size_t)row * TN + col] = (_Float16)v;
        else        ((float*)Cout)[(size_t)row * TN + col] = v;
      }
  }
}

// ---------------------------------------------------------------------------
// Barrier-free split-bf16 GEMM for offsets (precision-critical): 3 MFMAs
// (hh+hl+lh).  A fp32 (split in regs), Bt split-bf16.  Epilogue fuses
// (acc + boff + refpt) * W - 0.5 -> pixel coords, fp32 out.
// ---------------------------------------------------------------------------
__global__ __launch_bounds__(256, 2) void gemm_offs(
    const float* __restrict__ A, const short* __restrict__ Bth,
    const short* __restrict__ Btl, const float* __restrict__ boff,
    const float* __restrict__ refpts, float* __restrict__ C)
{
  constexpr int JF = 8;   // TN = 256
  const int tid = threadIdx.x, lane = tid & 63, wave = tid >> 6;
  const int l15 = lane & 15, quad = lane >> 4;
  const int wr = (wave & 1) * 64, wc = (wave >> 1) * 128;
  const int rowA = blockIdx.x * 128 + wr + l15;
  const int kq = quad * 8;

  float4 a_pf[8];
  auto loadA = [&](int kk, float4* dst) {
#pragma unroll
    for (int i = 0; i < 4; ++i) {
      dst[2 * i]     = *(const float4*)&A[(size_t)(rowA + i * 16) * 256 + kk];
      dst[2 * i + 1] = *(const float4*)&A[(size_t)(rowA + i * 16) * 256 + kk + 4];
    }
  };

  loadA(kq, a_pf);
  fv4 acc[4][JF] = {};

  for (int k0 = 0; k0 < 256; k0 += 32) {
    sv8 ah[4], al[4];
#pragma unroll
    for (int i = 0; i < 4; ++i) {
      const float fvv[8] = {a_pf[2 * i].x, a_pf[2 * i].y, a_pf[2 * i].z, a_pf[2 * i].w,
                            a_pf[2 * i + 1].x, a_pf[2 * i + 1].y, a_pf[2 * i + 1].z, a_pf[2 * i + 1].w};
      sv8 hh, ll;
#pragma unroll
      for (int e = 0; e < 8; ++e) {
        const unsigned short h = f2bf(fvv[e]);
        hh[e] = (short)h;
        ll[e] = (short)f2bf(fvv[e] - bf2f(h));
      }
      ah[i] = hh; al[i] = ll;
    }
    if (k0 < 224) loadA(k0 + 32 + kq, a_pf);
#pragma unroll
    for (int j = 0; j < JF; ++j) {
      const sv8 bh = *(const sv8*)&Bth[(size_t)(wc + j * 16 + l15) * 256 + k0 + kq];
      const sv8 bl = *(const sv8*)&Btl[(size_t)(wc + j * 16 + l15) * 256 + k0 + kq];
#pragma unroll
      for (int i = 0; i < 4; ++i) {
        acc[i][j] = __builtin_amdgcn_mfma_f32_16x16x32_bf16(ah[i], bh, acc[i][j], 0, 0, 0);
        acc[i][j] = __builtin_amdgcn_mfma_f32_16x16x32_bf16(ah[i], bl, acc[i][j], 0, 0, 0);
        acc[i][j] = __builtin_amdgcn_mfma_f32_16x16x32_bf16(al[i], bh, acc[i][j], 0, 0, 0);
      }
    }
  }

  // Epilogue: col c = (((m*4+l)*4+p)*2+xy); write (acc+boff+ref)*W - 0.5
#pragma unroll
  for (int j = 0; j < JF; ++j) {
    const int c = wc + j * 16 + l15;
    const int xy = c & 1, l = (c >> 3) & 3;
    const float Wl = (float)(128 >> l);
    const float bj = boff[c];
#pragma unroll
    for (int i = 0; i < 4; ++i)
#pragma unroll
      for (int rg = 0; rg < 4; ++rg) {
        const int row = blockIdx.x * 128 + wr + i * 16 + quad * 4 + rg;
        const float ref = refpts[(size_t)row * 8 + l * 2 + xy];
        C[(size_t)row * 256 + c] = (acc[i][j][rg] + bj + ref) * Wl - 0.5f;
      }
  }
}

// ---------------------------------------------------------------------------
// Sampler: 256 thr / block, 8 queries per block.
//  softmax (64 thr) -> s_attn[p*64+q*8+m]
//  phase 1 (256 thr x 4): corner index+weight packed to 32 bits
//    (idx 15b | round(w*2^17) 17b), written lane-consecutively.
//  phase 2: lane=(q,m,j): 64 x {b32 LDS (16 words, 4-way bcast), dwordx4
//    gather of 8 f16 dims, 8 fma}.  Writes out_pre f16.
// ---------------------------------------------------------------------------
__global__ __launch_bounds__(256) void sample_kernel(
    const _Float16* __restrict__ value16,  // (B, LEN_IN, 256) f16
    const float* __restrict__ coords,      // (B, LQ, 256) f32 pixel coords
    const _Float16* __restrict__ logits16, // (B, LQ, 128) f16
    _Float16* __restrict__ outp16)         // (B, LQ, 256) f16
{
  __shared__ unsigned s_pair[4][1024];
  __shared__ float    s_attn[1024];

  const int tid = threadIdx.x;
  const int qBase = blockIdx.x * 8;

  if (tid < 64) {   // softmax per (q,m) over 16
    const int q = tid >> 3, m = tid & 7;
    const hv8* lp = (const hv8*)&logits16[(size_t)(qBase + q) * 128 + m * 16];
    const hv8 w0 = lp[0], w1 = lp[1];
    float w[16];
#pragma unroll
    for (int e = 0; e < 8; ++e) { w[e] = (float)w0[e]; w[8 + e] = (float)w1[e]; }
    float mx = w[0];
#pragma unroll
    for (int i = 1; i < 16; ++i) mx = fmaxf(mx, w[i]);
    float sum = 0.f;
#pragma unroll
    for (int i = 0; i < 16; ++i) { w[i] = expf(w[i] - mx); sum += w[i]; }
    const float inv = 1.f / sum;
#pragma unroll
    for (int p = 0; p < 16; ++p) s_attn[p * 64 + tid] = w[p] * inv;
  }
  __syncthreads();

#pragma unroll
  for (int k = 0; k < 4; ++k) {
    const int i = tid + 256 * k;
    const int p = i >> 6, q = (i >> 3) & 7, m = i & 7;
    const int l = p >> 2, pp = p & 3;
    const int qg = qBase + q;
    const float2 of = *(const float2*)&coords[(size_t)qg * 256 + ((m * 4 + l) * 4 + pp) * 2];
    const float aw = s_attn[i];
    const int W = 128 >> l;
    const int st = (l == 0) ? 0 : (l == 1) ? 16384 : (l == 2) ? 20480 : 21504;
    const float x = of.x, y = of.y;   // already pixel coords
    const float xf = floorf(x), yf = floorf(y);
    const int x0 = (int)xf, y0 = (int)yf;
    const float wx = x - xf, wy = y - yf;
#pragma unroll
    for (int c = 0; c < 4; ++c) {
      const int dx = c & 1, dy = c >> 1;
      const int xi = x0 + dx, yi = y0 + dy;
      const bool valid = (xi >= 0) & (xi < W) & (yi >= 0) & (yi < W);
      const float w = (dx ? wx : 1.f - wx) * (dy ? wy : 1.f - wy) * aw;
      unsigned wq = (unsigned)(w * 131072.f + 0.5f);
      wq = wq > 131071u ? 131071u : wq;
      const unsigned idx = (unsigned)(st + yi * W + xi);
      s_pair[c][i] = valid ? (idx | (wq << 15)) : 0u;
    }
  }
  __syncthreads();

  const int wave = tid >> 6, lane = tid & 63;
  const int qloc = wave * 2 + (lane >> 5);
  const int sub = lane & 31, m = sub >> 2, j = sub & 3;
  const int qg = qBase + qloc;
  const int n = (qg >= LEN_IN) ? 1 : 0;
  const char* base = (const char*)value16 + (size_t)n * LEN_IN * 512 + m * 64 + j * 16;
  const int lb = qloc * 8 + m;

  float acc8[8] = {0.f, 0.f, 0.f, 0.f, 0.f, 0.f, 0.f, 0.f};
#pragma unroll 8
  for (int i = 0; i < 64; ++i) {
    const int c = i & 3, p = i >> 2;
    const unsigned u = s_pair[c][p * 64 + lb];
    const float w = (float)(u >> 15) * (1.f / 131072.f);
    const hv8 v = *(const hv8*)(base + (size_t)(u & 32767u) * 512);
#pragma unroll
    for (int e = 0; e < 8; ++e) acc8[e] = fmaf(w, (float)v[e], acc8[e]);
  }

  hv8 o;
#pragma unroll
  for (int e = 0; e < 8; ++e) o[e] = (_Float16)acc8[e];
  *(hv8*)&outp16[(size_t)qg * 256 + m * 32 + j * 8] = o;
}

// ---------------------------------------------------------------------------
extern "C" void kernel_launch(void* const* d_in, const int* in_sizes, int n_in,
                              void* d_out, int out_size, void* d_ws, size_t ws_size,
                              hipStream_t stream) {
  const float* query   = (const float*)d_in[0];
  const float* refpts  = (const float*)d_in[1];
  const float* flatten = (const float*)d_in[2];
  const float* Wv   = (const float*)d_in[5];
  const float* bv   = (const float*)d_in[6];
  const float* Woff = (const float*)d_in[7];
  const float* boff = (const float*)d_in[8];
  const float* Wa   = (const float*)d_in[9];
  const float* ba   = (const float*)d_in[10];
  const float* Wo   = (const float*)d_in[11];
  const float* bo   = (const float*)d_in[12];
  float* out = (float*)d_out;

  // Workspace (~101 MB): value16 | coords | logits16 | outp16 | weights
  const size_t NE = (size_t)MROWS * 256;            // 11,141,120
  _Float16* value16  = (_Float16*)d_ws;             // NE halves
  float*    coords   = (float*)(value16 + NE);      // NE floats
  _Float16* logits16 = (_Float16*)(coords + NE);    // NE/2 halves
  _Float16* outp16   = logits16 + NE / 2;           // NE halves
  _Float16* WvT16    = outp16 + NE;
  short*    WoffTh   = (short*)(WvT16 + 256 * 256);
  short*    WoffTl   = WoffTh + 256 * 256;
  _Float16* WaT16    = (_Float16*)(WoffTl + 256 * 256);
  _Float16* WoT16    = WaT16 + 128 * 256;

  const dim3 blk(256);
  const int mtiles = MROWS / 128;  // 340

  cvt_weights<<<dim3(896), blk, 0, stream>>>(Wv, Woff, Wa, Wo,
      WvT16, WoffTh, WoffTl, WaT16, WoT16);

  // value = f16(flatten @ Wv + bv)
  gemm_f16d<256, 1, 1><<<dim3(mtiles), blk, 0, stream>>>(flatten, WvT16, bv, value16);
  // coords = (query @ Woff + boff + ref) * W - 0.5   (split-bf16, fp32 out)
  gemm_offs<<<dim3(mtiles), blk, 0, stream>>>(query, WoffTh, WoffTl, boff, refpts, coords);
  // logits = f16(query @ Wa + ba)
  gemm_f16d<128, 1, 1><<<dim3(mtiles), blk, 0, stream>>>(query, WaT16, ba, logits16);
  // sampling -> out_pre (f16)
  sample_kernel<<<dim3(MROWS / 8), blk, 0, stream>>>(value16, coords, logits16, outp16);
  // out = out_pre @ Wo + bo  (f16 MFMA, fp32 out)
  gemm_f16d<256, 0, 0><<<dim3(mtiles), blk, 0, stream>>>(outp16, WoT16, bo, out);
}

// Round 6
// 316.637 us; speedup vs baseline: 1.1967x; 1.1967x over previous
//
#include <hip/hip_runtime.h>
#include <cstdint>
#include <cstddef>

// Static problem geometry
#define LEN_IN  21760
#define BATCH   2
#define MROWS   (BATCH * LEN_IN)   // 43520 = 64 * 680
// Levels: (128,128),(64,64),(32,32),(16,16); starts 0,16384,20480,21504

typedef short    sv8 __attribute__((ext_vector_type(8)));   // 8 bf16
typedef _Float16 hv8 __attribute__((ext_vector_type(8)));   // 8 f16
typedef float    fv4 __attribute__((ext_vector_type(4)));

__device__ __forceinline__ unsigned short f2bf(float f) {
  unsigned u = __float_as_uint(f);
  u += 0x7fff + ((u >> 16) & 1);           // RNE
  return (unsigned short)(u >> 16);
}
__device__ __forceinline__ float bf2f(unsigned short s) {
  return __uint_as_float(((unsigned)s) << 16);
}

// ---------------------------------------------------------------------------
// Weight prep: transpose K-major -> [N][K]. Wv, Wa, Wo -> f16; Woff -> split.
// ---------------------------------------------------------------------------
__global__ __launch_bounds__(256) void cvt_weights(
    const float* __restrict__ Wv, const float* __restrict__ Woff,
    const float* __restrict__ Wa, const float* __restrict__ Wo,
    _Float16* __restrict__ WvT, short* __restrict__ WoffTh, short* __restrict__ WoffTl,
    _Float16* __restrict__ WaT, _Float16* __restrict__ WoT)
{
  const int b = blockIdx.x, k = threadIdx.x;
  if (b < 256) {
    WvT[(size_t)b * 256 + k] = (_Float16)Wv[(size_t)k * 256 + b];
  } else if (b < 512) {
    const int n = b - 256;
    const float v = Woff[(size_t)k * 256 + n];
    const unsigned short h = f2bf(v);
    WoffTh[(size_t)n * 256 + k] = h;
    WoffTl[(size_t)n * 256 + k] = f2bf(v - bf2f(h));
  } else if (b < 640) {
    const int n = b - 512;
    WaT[(size_t)n * 256 + k] = (_Float16)Wa[(size_t)k * 128 + n];
  } else {
    const int n = b - 640;
    WoT[(size_t)n * 256 + k] = (_Float16)Wo[(size_t)k * 256 + n];
  }
}

// ---------------------------------------------------------------------------
// Staged f16 MFMA GEMM, 64 x TN tile, 256 thr = 4 waves side-by-side
// (wave tile 64 x TN/4), K=256 in 8 chunks of 32, register prefetch.
// LDS stride 40 halves (conflict-free b128 frag reads, m97 pattern).
// AF32: A fp32 (convert in staging) else f16.
// OUTMODE 0: fp32 row-major [.][TN]; 1: f16 row-major; 2: f16 head planes
//   value16[((n*8+m)*LEN_IN + pix)*32 + d].
// ---------------------------------------------------------------------------
template<int TN, int AF32, int OUTMODE>
__global__ __launch_bounds__(256, 4) void gemm_f16t(
    const void* __restrict__ Ap, const _Float16* __restrict__ Bt,
    const float* __restrict__ bias, void* __restrict__ Cout)
{
  constexpr int JF = TN / 64;   // j-frags per wave
  constexpr int NB = TN / 64;   // B staging passes
  __shared__ _Float16 As[64 * 40];
  __shared__ _Float16 Bs[TN * 40];

  const int tid = threadIdx.x, lane = tid & 63, wave = tid >> 6;
  const int l15 = lane & 15, quad = lane >> 4;
  const int wc = wave * (TN / 4);
  const int rowBase = blockIdx.x * 64;
  const int rs = tid >> 2, ks = (tid & 3) * 8;

  float4 a32[2]; hv8 a16; hv8 bpf[NB];
  auto loadAB = [&](int k0) {
    if constexpr (AF32) {
      const float* A = (const float*)Ap;
      a32[0] = *(const float4*)&A[(size_t)(rowBase + rs) * 256 + k0 + ks];
      a32[1] = *(const float4*)&A[(size_t)(rowBase + rs) * 256 + k0 + ks + 4];
    } else {
      const _Float16* A = (const _Float16*)Ap;
      a16 = *(const hv8*)&A[(size_t)(rowBase + rs) * 256 + k0 + ks];
    }
#pragma unroll
    for (int p = 0; p < NB; ++p)
      bpf[p] = *(const hv8*)&Bt[(size_t)(p * 64 + rs) * 256 + k0 + ks];
  };

  loadAB(0);
  fv4 acc[4][JF] = {};

  for (int k0 = 0; k0 < 256; k0 += 32) {
    if (k0) __syncthreads();
    if constexpr (AF32) {
      const float fa[8] = {a32[0].x, a32[0].y, a32[0].z, a32[0].w,
                           a32[1].x, a32[1].y, a32[1].z, a32[1].w};
      hv8 h;
#pragma unroll
      for (int e = 0; e < 8; ++e) h[e] = (_Float16)fa[e];
      *(hv8*)&As[rs * 40 + ks] = h;
    } else {
      *(hv8*)&As[rs * 40 + ks] = a16;
    }
#pragma unroll
    for (int p = 0; p < NB; ++p) *(hv8*)&Bs[(p * 64 + rs) * 40 + ks] = bpf[p];
    __syncthreads();
    if (k0 < 224) loadAB(k0 + 32);

    hv8 af[4];
#pragma unroll
    for (int i = 0; i < 4; ++i)
      af[i] = *(const hv8*)&As[(i * 16 + l15) * 40 + quad * 8];
#pragma unroll
    for (int j = 0; j < JF; ++j) {
      const hv8 bf = *(const hv8*)&Bs[(wc + j * 16 + l15) * 40 + quad * 8];
#pragma unroll
      for (int i = 0; i < 4; ++i)
        acc[i][j] = __builtin_amdgcn_mfma_f32_16x16x32_f16(af[i], bf, acc[i][j], 0, 0, 0);
    }
  }

#pragma unroll
  for (int j = 0; j < JF; ++j) {
    const int col = wc + j * 16 + l15;
    const float bj = bias[col];
#pragma unroll
    for (int i = 0; i < 4; ++i)
#pragma unroll
      for (int rg = 0; rg < 4; ++rg) {
        const int row = rowBase + i * 16 + quad * 4 + rg;
        const float v = acc[i][j][rg] + bj;
        if constexpr (OUTMODE == 0) {
          ((float*)Cout)[(size_t)row * TN + col] = v;
        } else if constexpr (OUTMODE == 1) {
          ((_Float16*)Cout)[(size_t)row * TN + col] = (_Float16)v;
        } else {
          const int n = (row >= LEN_IN) ? 1 : 0;
          const int pix = row - n * LEN_IN;
          const int m = col >> 5, d = col & 31;
          ((_Float16*)Cout)[((size_t)(n * 8 + m) * LEN_IN + pix) * 32 + d] = (_Float16)v;
        }
      }
  }
}

// ---------------------------------------------------------------------------
// Staged split-bf16 GEMM for offsets (3 MFMAs: hh+hl+lh). 64x256 tile.
// Epilogue fuses (acc + boff + refpt) * W - 0.5 -> pixel coords fp32.
// ---------------------------------------------------------------------------
__global__ __launch_bounds__(256, 3) void gemm_offs(
    const float* __restrict__ A, const short* __restrict__ Bth,
    const short* __restrict__ Btl, const float* __restrict__ boff,
    const float* __restrict__ refpts, float* __restrict__ C)
{
  __shared__ short Ash[64 * 40], Asl[64 * 40];
  __shared__ short Bsh[256 * 40], Bsl[256 * 40];

  const int tid = threadIdx.x, lane = tid & 63, wave = tid >> 6;
  const int l15 = lane & 15, quad = lane >> 4;
  const int wc = wave * 64;
  const int rowBase = blockIdx.x * 64;
  const int rs = tid >> 2, ks = (tid & 3) * 8;

  float4 a32[2]; sv8 bhp[4], blp[4];
  auto loadAB = [&](int k0) {
    a32[0] = *(const float4*)&A[(size_t)(rowBase + rs) * 256 + k0 + ks];
    a32[1] = *(const float4*)&A[(size_t)(rowBase + rs) * 256 + k0 + ks + 4];
#pragma unroll
    for (int p = 0; p < 4; ++p) {
      bhp[p] = *(const sv8*)&Bth[(size_t)(p * 64 + rs) * 256 + k0 + ks];
      blp[p] = *(const sv8*)&Btl[(size_t)(p * 64 + rs) * 256 + k0 + ks];
    }
  };

  loadAB(0);
  fv4 acc[4][4] = {};

  for (int k0 = 0; k0 < 256; k0 += 32) {
    if (k0) __syncthreads();
    {
      const float fa[8] = {a32[0].x, a32[0].y, a32[0].z, a32[0].w,
                           a32[1].x, a32[1].y, a32[1].z, a32[1].w};
      sv8 hh, ll;
#pragma unroll
      for (int e = 0; e < 8; ++e) {
        const unsigned short h = f2bf(fa[e]);
        hh[e] = (short)h;
        ll[e] = (short)f2bf(fa[e] - bf2f(h));
      }
      *(sv8*)&Ash[rs * 40 + ks] = hh;
      *(sv8*)&Asl[rs * 40 + ks] = ll;
    }
#pragma unroll
    for (int p = 0; p < 4; ++p) {
      *(sv8*)&Bsh[(p * 64 + rs) * 40 + ks] = bhp[p];
      *(sv8*)&Bsl[(p * 64 + rs) * 40 + ks] = blp[p];
    }
    __syncthreads();
    if (k0 < 224) loadAB(k0 + 32);

    sv8 ah[4], al[4];
#pragma unroll
    for (int i = 0; i < 4; ++i) {
      ah[i] = *(const sv8*)&Ash[(i * 16 + l15) * 40 + quad * 8];
      al[i] = *(const sv8*)&Asl[(i * 16 + l15) * 40 + quad * 8];
    }
#pragma unroll
    for (int j = 0; j < 4; ++j) {
      const sv8 bh = *(const sv8*)&Bsh[(wc + j * 16 + l15) * 40 + quad * 8];
      const sv8 bl = *(const sv8*)&Bsl[(wc + j * 16 + l15) * 40 + quad * 8];
#pragma unroll
      for (int i = 0; i < 4; ++i) {
        acc[i][j] = __builtin_amdgcn_mfma_f32_16x16x32_bf16(ah[i], bh, acc[i][j], 0, 0, 0);
        acc[i][j] = __builtin_amdgcn_mfma_f32_16x16x32_bf16(ah[i], bl, acc[i][j], 0, 0, 0);
        acc[i][j] = __builtin_amdgcn_mfma_f32_16x16x32_bf16(al[i], bh, acc[i][j], 0, 0, 0);
      }
    }
  }

  // col c = (((m*4+l)*4+p)*2+xy); write (acc + boff + ref) * W - 0.5
#pragma unroll
  for (int j = 0; j < 4; ++j) {
    const int c = wc + j * 16 + l15;
    const int xy = c & 1, l = (c >> 3) & 3;
    const float Wl = (float)(128 >> l);
    const float bj = boff[c];
#pragma unroll
    for (int i = 0; i < 4; ++i)
#pragma unroll
      for (int rg = 0; rg < 4; ++rg) {
        const int row = rowBase + i * 16 + quad * 4 + rg;
        const float ref = refpts[(size_t)row * 8 + l * 2 + xy];
        C[(size_t)row * 256 + c] = (acc[i][j][rg] + bj + ref) * Wl - 0.5f;
      }
  }
}

// ---------------------------------------------------------------------------
// Sampler: 256 thr / block, 8 queries. Value in per-head planes
// [(n*8+m)][pixel][32ch f16] so x-corner pairs share cache lines.
//  softmax (64 thr) -> s_attn[p*64+q*8+m]
//  phase 1: item i=p*64+q*8+m, 4 corners packed (idx15 | f16(w)<<16) as one
//    uint4 -> s_pair[i*4..] (b128 write).
//  phase 2: lane=(q,m,j): 16 x {ds_read_b128 -> 4 gathers dwordx4 + 4x8 fma}.
// ---------------------------------------------------------------------------
__global__ __launch_bounds__(256, 6) void sample_kernel(
    const _Float16* __restrict__ value16,  // head planes
    const float* __restrict__ coords,      // (B, LQ, 256) pixel coords
    const _Float16* __restrict__ logits16, // (B, LQ, 128)
    _Float16* __restrict__ outp16)         // (B, LQ, 256)
{
  __shared__ unsigned s_pair[4096];
  __shared__ float    s_attn[1024];

  const int tid = threadIdx.x;
  const int qBase = blockIdx.x * 8;

  if (tid < 64) {   // softmax per (q,m) over 16
    const hv8* lp = (const hv8*)&logits16[(size_t)(qBase + (tid >> 3)) * 128 + (tid & 7) * 16];
    const hv8 w0 = lp[0], w1 = lp[1];
    float w[16];
#pragma unroll
    for (int e = 0; e < 8; ++e) { w[e] = (float)w0[e]; w[8 + e] = (float)w1[e]; }
    float mx = w[0];
#pragma unroll
    for (int i = 1; i < 16; ++i) mx = fmaxf(mx, w[i]);
    float sum = 0.f;
#pragma unroll
    for (int i = 0; i < 16; ++i) { w[i] = expf(w[i] - mx); sum += w[i]; }
    const float inv = 1.f / sum;
#pragma unroll
    for (int p = 0; p < 16; ++p) s_attn[p * 64 + tid] = w[p] * inv;
  }
  __syncthreads();

#pragma unroll
  for (int k = 0; k < 4; ++k) {
    const int i = tid + 256 * k;
    const int p = i >> 6, q = (i >> 3) & 7, m = i & 7;
    const int l = p >> 2, pp = p & 3;
    const int qg = qBase + q;
    const float2 of = *(const float2*)&coords[(size_t)qg * 256 + ((m * 4 + l) * 4 + pp) * 2];
    const float aw = s_attn[i];
    const int W = 128 >> l;
    const int st = (l == 0) ? 0 : (l == 1) ? 16384 : (l == 2) ? 20480 : 21504;
    const float xf = floorf(of.x), yf = floorf(of.y);
    const int x0 = (int)xf, y0 = (int)yf;
    const float wx = of.x - xf, wy = of.y - yf;
    uint4 rec;
    unsigned* rp = &rec.x;
#pragma unroll
    for (int c = 0; c < 4; ++c) {
      const int dx = c & 1, dy = c >> 1;
      const int xi = x0 + dx, yi = y0 + dy;
      const bool valid = (xi >= 0) & (xi < W) & (yi >= 0) & (yi < W);
      const float w = (dx ? wx : 1.f - wx) * (dy ? wy : 1.f - wy) * aw;
      union { _Float16 h; unsigned short s; } pk;
      pk.h = (_Float16)w;
      const unsigned idx = (unsigned)(st + yi * W + xi);
      rp[c] = valid ? (idx | ((unsigned)pk.s << 16)) : 0u;
    }
    *(uint4*)&s_pair[i * 4] = rec;
  }
  __syncthreads();

  const int wave = tid >> 6, lane = tid & 63;
  const int qloc = wave * 2 + (lane >> 5);
  const int sub = lane & 31, m = sub >> 2, j = sub & 3;
  const int qg = qBase + qloc;
  const int n = (qg >= LEN_IN) ? 1 : 0;
  const char* base = (const char*)value16 + (size_t)(n * 8 + m) * LEN_IN * 64 + j * 16;
  const int lb = qloc * 8 + m;

  float acc8[8] = {0.f, 0.f, 0.f, 0.f, 0.f, 0.f, 0.f, 0.f};
#pragma unroll 4
  for (int p = 0; p < 16; ++p) {
    const uint4 u4 = *(const uint4*)&s_pair[(p * 64 + lb) * 4];
    const unsigned uu[4] = {u4.x, u4.y, u4.z, u4.w};
#pragma unroll
    for (int c = 0; c < 4; ++c) {
      const unsigned u = uu[c];
      union { unsigned short s; _Float16 h; } pk;
      pk.s = (unsigned short)(u >> 16);
      const float w = (float)pk.h;
      const hv8 v = *(const hv8*)(base + (size_t)(u & 32767u) * 64);
#pragma unroll
      for (int e = 0; e < 8; ++e) acc8[e] = fmaf(w, (float)v[e], acc8[e]);
    }
  }

  hv8 o;
#pragma unroll
  for (int e = 0; e < 8; ++e) o[e] = (_Float16)acc8[e];
  *(hv8*)&outp16[(size_t)qg * 256 + m * 32 + j * 8] = o;
}

// ---------------------------------------------------------------------------
extern "C" void kernel_launch(void* const* d_in, const int* in_sizes, int n_in,
                              void* d_out, int out_size, void* d_ws, size_t ws_size,
                              hipStream_t stream) {
  const float* query   = (const float*)d_in[0];
  const float* refpts  = (const float*)d_in[1];
  const float* flatten = (const float*)d_in[2];
  const float* Wv   = (const float*)d_in[5];
  const float* bv   = (const float*)d_in[6];
  const float* Woff = (const float*)d_in[7];
  const float* boff = (const float*)d_in[8];
  const float* Wa   = (const float*)d_in[9];
  const float* ba   = (const float*)d_in[10];
  const float* Wo   = (const float*)d_in[11];
  const float* bo   = (const float*)d_in[12];
  float* out = (float*)d_out;

  // Workspace (~101 MB): value16 | coords | logits16 | outp16 | weights
  const size_t NE = (size_t)MROWS * 256;            // 11,141,120
  _Float16* value16  = (_Float16*)d_ws;             // NE halves (head planes)
  float*    coords   = (float*)(value16 + NE);      // NE floats
  _Float16* logits16 = (_Float16*)(coords + NE);    // NE/2 halves
  _Float16* outp16   = logits16 + NE / 2;           // NE halves
  _Float16* WvT16    = outp16 + NE;
  short*    WoffTh   = (short*)(WvT16 + 256 * 256);
  short*    WoffTl   = WoffTh + 256 * 256;
  _Float16* WaT16    = (_Float16*)(WoffTl + 256 * 256);
  _Float16* WoT16    = WaT16 + 128 * 256;

  const dim3 blk(256);
  const int mtiles = MROWS / 64;   // 680

  cvt_weights<<<dim3(896), blk, 0, stream>>>(Wv, Woff, Wa, Wo,
      WvT16, WoffTh, WoffTl, WaT16, WoT16);

  // value = f16(flatten @ Wv + bv) -> head planes
  gemm_f16t<256, 1, 2><<<dim3(mtiles), blk, 0, stream>>>(flatten, WvT16, bv, value16);
  // coords = (query @ Woff + boff + ref) * W - 0.5
  gemm_offs<<<dim3(mtiles), blk, 0, stream>>>(query, WoffTh, WoffTl, boff, refpts, coords);
  // logits = f16(query @ Wa + ba)
  gemm_f16t<128, 1, 1><<<dim3(mtiles), blk, 0, stream>>>(query, WaT16, ba, logits16);
  // sampling -> out_pre (f16)
  sample_kernel<<<dim3(MROWS / 8), blk, 0, stream>>>(value16, coords, logits16, outp16);
  // out = out_pre @ Wo + bo (fp32 to d_out)
  gemm_f16t<256, 0, 0><<<dim3(mtiles), blk, 0, stream>>>(outp16, WoT16, bo, out);
}

// Round 7
// 295.068 us; speedup vs baseline: 1.2842x; 1.0731x over previous
//
#include <hip/hip_runtime.h>
#include <cstdint>
#include <cstddef>

// Static problem geometry
#define LEN_IN  21760
#define BATCH   2
#define MROWS   (BATCH * LEN_IN)   // 43520 = 64 * 680
// Levels: (128,128),(64,64),(32,32),(16,16); starts 0,16384,20480,21504

typedef _Float16 hv8 __attribute__((ext_vector_type(8)));   // 8 f16
typedef float    fv4 __attribute__((ext_vector_type(4)));

#define WAIT_LGKM0() __builtin_amdgcn_s_waitcnt(0xC07F)   // lgkmcnt(0) only
#define RAW_BARRIER() __builtin_amdgcn_s_barrier()

// ---------------------------------------------------------------------------
// Weight prep: coalesced 64x64 LDS transpose. K-major [K][N] -> [N][K] f16.
// Woff -> f16-split: rows [0,256) = hi, [256,512) = lo residual.
// Grid 56: 0-15 Wv, 16-31 Woff, 32-39 Wa (N=128), 40-55 Wo.
// ---------------------------------------------------------------------------
__global__ __launch_bounds__(256) void cvt_weights(
    const float* __restrict__ Wv, const float* __restrict__ Woff,
    const float* __restrict__ Wa, const float* __restrict__ Wo,
    _Float16* __restrict__ WvT, _Float16* __restrict__ WoffT2,
    _Float16* __restrict__ WaT, _Float16* __restrict__ WoT)
{
  __shared__ float t[64][65];
  const int id = blockIdx.x, tid = threadIdx.x;
  const int c = tid & 63, r4 = tid >> 6;

  const float* src; _Float16* dst; int N; bool split = false; int nt, kt;
  if (id < 16)      { src = Wv;   dst = WvT;    N = 256; nt = id & 3;        kt = id >> 2; }
  else if (id < 32) { src = Woff; dst = WoffT2; N = 256; nt = (id - 16) & 3; kt = (id - 16) >> 2; split = true; }
  else if (id < 40) { src = Wa;   dst = WaT;    N = 128; nt = (id - 32) & 1; kt = (id - 32) >> 1; }
  else              { src = Wo;   dst = WoT;    N = 256; nt = (id - 40) & 3; kt = (id - 40) >> 2; }
  const int nb = nt * 64, kb = kt * 64;

#pragma unroll
  for (int rr = 0; rr < 16; ++rr) {
    const int r = rr * 4 + r4;
    t[r][c] = src[(size_t)(kb + r) * N + nb + c];   // coalesced
  }
  __syncthreads();
#pragma unroll
  for (int rr = 0; rr < 16; ++rr) {
    const int r = rr * 4 + r4;                      // n-offset
    const float v = t[c][r];                        // 65-stride: conflict-free
    const _Float16 h = (_Float16)v;
    dst[(size_t)(nb + r) * 256 + kb + c] = h;       // coalesced
    if (split)
      dst[(size_t)(256 + nb + r) * 256 + kb + c] = (_Float16)(v - (float)h);
  }
}

// ---------------------------------------------------------------------------
// Pipelined f16 MFMA GEMM, 64 x TN tile, 256 thr = 4 waves side-by-side.
// A: 4-deep register pipeline (HBM loads stay in flight across barriers).
// B: 1-deep register prefetch (L2-hot). LDS double-buffered; ONE raw barrier
// per K-iter with lgkmcnt(0)-only wait (no vmcnt drain!).
// AF32: A fp32 (cvt in regs) else f16.
// OUTMODE 0: fp32 row-major; 1: f16 row-major; 2: f16 head planes.
// ---------------------------------------------------------------------------
template<int TN, int AF32, int OUTMODE>
__global__ __launch_bounds__(256) void gemm_pipe(
    const void* __restrict__ Ap, const _Float16* __restrict__ Bt,
    const float* __restrict__ bias, void* __restrict__ Cout)
{
  constexpr int NB = TN / 64;
  constexpr int JF = TN / 64;
  __shared__ _Float16 As[2][64 * 40];
  __shared__ _Float16 Bs[2][TN * 40];

  const int tid = threadIdx.x, lane = tid & 63, wave = tid >> 6;
  const int l15 = lane & 15, quad = lane >> 4;
  const int wc = wave * (TN / 4);
  const int rowBase = blockIdx.x * 64;
  const int rs = tid >> 2, ks = (tid & 3) * 8;

  const float*    A32 = (const float*)Ap;
  const _Float16* A16 = (const _Float16*)Ap;

  float4 pa[4][2];
  hv8    pa16[4];
  hv8    pb[NB];

  auto issueA = [&](int it) {
    const int k0 = it * 32, s = it & 3;
    if constexpr (AF32) {
      pa[s][0] = *(const float4*)&A32[(size_t)(rowBase + rs) * 256 + k0 + ks];
      pa[s][1] = *(const float4*)&A32[(size_t)(rowBase + rs) * 256 + k0 + ks + 4];
    } else {
      pa16[s] = *(const hv8*)&A16[(size_t)(rowBase + rs) * 256 + k0 + ks];
    }
  };
  auto issueB = [&](int it) {
    const int k0 = it * 32;
#pragma unroll
    for (int p = 0; p < NB; ++p)
      pb[p] = *(const hv8*)&Bt[(size_t)(p * 64 + rs) * 256 + k0 + ks];
  };

  issueA(0); issueA(1); issueA(2); issueA(3);
  issueB(0);

  fv4 acc[4][JF] = {};

#pragma unroll
  for (int it = 0; it < 8; ++it) {
    const int sa = it & 3, sb = it & 1;
    if constexpr (AF32) {
      const float4 f0 = pa[sa][0], f1 = pa[sa][1];
      const float fa[8] = {f0.x, f0.y, f0.z, f0.w, f1.x, f1.y, f1.z, f1.w};
      hv8 h;
#pragma unroll
      for (int e = 0; e < 8; ++e) h[e] = (_Float16)fa[e];
      *(hv8*)&As[sb][rs * 40 + ks] = h;
    } else {
      *(hv8*)&As[sb][rs * 40 + ks] = pa16[sa];
    }
#pragma unroll
    for (int p = 0; p < NB; ++p)
      *(hv8*)&Bs[sb][(p * 64 + rs) * 40 + ks] = pb[p];
    if (it + 4 < 8) issueA(it + 4);
    if (it + 1 < 8) issueB(it + 1);
    WAIT_LGKM0();
    RAW_BARRIER();

    hv8 af[4];
#pragma unroll
    for (int i = 0; i < 4; ++i)
      af[i] = *(const hv8*)&As[sb][(i * 16 + l15) * 40 + quad * 8];
#pragma unroll
    for (int j = 0; j < JF; ++j) {
      const hv8 bf = *(const hv8*)&Bs[sb][(wc + j * 16 + l15) * 40 + quad * 8];
#pragma unroll
      for (int i = 0; i < 4; ++i)
        acc[i][j] = __builtin_amdgcn_mfma_f32_16x16x32_f16(af[i], bf, acc[i][j], 0, 0, 0);
    }
    // No trailing barrier: buffers alternate; re-use of buf sb at it+2 is
    // fenced by barrier(it+1)'s lgkmcnt(0) (all frag reads of it complete).
  }

#pragma unroll
  for (int j = 0; j < JF; ++j) {
    const int col = wc + j * 16 + l15;
    const float bj = bias[col];
#pragma unroll
    for (int i = 0; i < 4; ++i)
#pragma unroll
      for (int rg = 0; rg < 4; ++rg) {
        const int row = rowBase + i * 16 + quad * 4 + rg;
        const float v = acc[i][j][rg] + bj;
        if constexpr (OUTMODE == 0) {
          ((float*)Cout)[(size_t)row * TN + col] = v;
        } else if constexpr (OUTMODE == 1) {
          ((_Float16*)Cout)[(size_t)row * TN + col] = (_Float16)v;
        } else {
          const int n = (row >= LEN_IN) ? 1 : 0;
          const int pix = row - n * LEN_IN;
          const int m = col >> 5, d = col & 31;
          ((_Float16*)Cout)[((size_t)(n * 8 + m) * LEN_IN + pix) * 32 + d] = (_Float16)v;
        }
      }
  }
}

// ---------------------------------------------------------------------------
// Pipelined offsets GEMM, f16-split (h+l ~ 22-bit mantissa): 3 MFMAs
// (hh+hl+lh). B2 = [512][256] f16 (rows 0-255 hi, 256-511 lo). Single-buffer
// LDS, two raw barriers per iter (lgkm-only). Epilogue fuses
// (acc + boff + ref) * W - 0.5 -> pixel coords fp32.
// ---------------------------------------------------------------------------
__global__ __launch_bounds__(256) void gemm_offs_pipe(
    const float* __restrict__ A, const _Float16* __restrict__ B2,
    const float* __restrict__ boff, const float* __restrict__ refpts,
    float* __restrict__ C)
{
  __shared__ _Float16 Ash[64 * 40], Asl[64 * 40];
  __shared__ _Float16 Bs[512 * 40];

  const int tid = threadIdx.x, lane = tid & 63, wave = tid >> 6;
  const int l15 = lane & 15, quad = lane >> 4;
  const int wc = wave * 64;
  const int rowBase = blockIdx.x * 64;
  const int rs = tid >> 2, ks = (tid & 3) * 8;

  float4 pa[4][2];
  hv8 pb[8];

  auto issueA = [&](int it) {
    const int k0 = it * 32, s = it & 3;
    pa[s][0] = *(const float4*)&A[(size_t)(rowBase + rs) * 256 + k0 + ks];
    pa[s][1] = *(const float4*)&A[(size_t)(rowBase + rs) * 256 + k0 + ks + 4];
  };
  auto issueB = [&](int it) {
    const int k0 = it * 32;
#pragma unroll
    for (int p = 0; p < 8; ++p)
      pb[p] = *(const hv8*)&B2[(size_t)(p * 64 + rs) * 256 + k0 + ks];
  };

  issueA(0); issueA(1); issueA(2); issueA(3);
  issueB(0);

  fv4 acc[4][4] = {};

#pragma unroll
  for (int it = 0; it < 8; ++it) {
    const int sa = it & 3;
    {
      const float4 f0 = pa[sa][0], f1 = pa[sa][1];
      const float fa[8] = {f0.x, f0.y, f0.z, f0.w, f1.x, f1.y, f1.z, f1.w};
      hv8 hh, ll;
#pragma unroll
      for (int e = 0; e < 8; ++e) {
        hh[e] = (_Float16)fa[e];
        ll[e] = (_Float16)(fa[e] - (float)hh[e]);
      }
      *(hv8*)&Ash[rs * 40 + ks] = hh;
      *(hv8*)&Asl[rs * 40 + ks] = ll;
    }
#pragma unroll
    for (int p = 0; p < 8; ++p)
      *(hv8*)&Bs[(p * 64 + rs) * 40 + ks] = pb[p];
    if (it + 4 < 8) issueA(it + 4);
    if (it + 1 < 8) issueB(it + 1);
    WAIT_LGKM0();
    RAW_BARRIER();

    hv8 ah[4], al[4];
#pragma unroll
    for (int i = 0; i < 4; ++i) {
      ah[i] = *(const hv8*)&Ash[(i * 16 + l15) * 40 + quad * 8];
      al[i] = *(const hv8*)&Asl[(i * 16 + l15) * 40 + quad * 8];
    }
#pragma unroll
    for (int j = 0; j < 4; ++j) {
      const hv8 bh = *(const hv8*)&Bs[(wc + j * 16 + l15) * 40 + quad * 8];
      const hv8 bl = *(const hv8*)&Bs[((256 + wc + j * 16 + l15)) * 40 + quad * 8];
#pragma unroll
      for (int i = 0; i < 4; ++i) {
        acc[i][j] = __builtin_amdgcn_mfma_f32_16x16x32_f16(ah[i], bh, acc[i][j], 0, 0, 0);
        acc[i][j] = __builtin_amdgcn_mfma_f32_16x16x32_f16(ah[i], bl, acc[i][j], 0, 0, 0);
        acc[i][j] = __builtin_amdgcn_mfma_f32_16x16x32_f16(al[i], bh, acc[i][j], 0, 0, 0);
      }
    }
    WAIT_LGKM0();   // all frag reads complete before next iter's writes
    RAW_BARRIER();
  }

  // col c = (((m*4+l)*4+p)*2+xy); write (acc + boff + ref) * W - 0.5
#pragma unroll
  for (int j = 0; j < 4; ++j) {
    const int c = wc + j * 16 + l15;
    const int xy = c & 1, l = (c >> 3) & 3;
    const float Wl = (float)(128 >> l);
    const float bj = boff[c];
#pragma unroll
    for (int i = 0; i < 4; ++i)
#pragma unroll
      for (int rg = 0; rg < 4; ++rg) {
        const int row = rowBase + i * 16 + quad * 4 + rg;
        const float ref = refpts[(size_t)row * 8 + l * 2 + xy];
        C[(size_t)row * 256 + c] = (acc[i][j][rg] + bj + ref) * Wl - 0.5f;
      }
  }
}

// ---------------------------------------------------------------------------
// Sampler (unchanged from round 6: 69.5 us, conflict-free, gather-bound).
// ---------------------------------------------------------------------------
__global__ __launch_bounds__(256, 6) void sample_kernel(
    const _Float16* __restrict__ value16,  // head planes
    const float* __restrict__ coords,      // (B, LQ, 256) pixel coords
    const _Float16* __restrict__ logits16, // (B, LQ, 128)
    _Float16* __restrict__ outp16)         // (B, LQ, 256)
{
  __shared__ unsigned s_pair[4096];
  __shared__ float    s_attn[1024];

  const int tid = threadIdx.x;
  const int qBase = blockIdx.x * 8;

  if (tid < 64) {   // softmax per (q,m) over 16
    const hv8* lp = (const hv8*)&logits16[(size_t)(qBase + (tid >> 3)) * 128 + (tid & 7) * 16];
    const hv8 w0 = lp[0], w1 = lp[1];
    float w[16];
#pragma unroll
    for (int e = 0; e < 8; ++e) { w[e] = (float)w0[e]; w[8 + e] = (float)w1[e]; }
    float mx = w[0];
#pragma unroll
    for (int i = 1; i < 16; ++i) mx = fmaxf(mx, w[i]);
    float sum = 0.f;
#pragma unroll
    for (int i = 0; i < 16; ++i) { w[i] = expf(w[i] - mx); sum += w[i]; }
    const float inv = 1.f / sum;
#pragma unroll
    for (int p = 0; p < 16; ++p) s_attn[p * 64 + tid] = w[p] * inv;
  }
  __syncthreads();

#pragma unroll
  for (int k = 0; k < 4; ++k) {
    const int i = tid + 256 * k;
    const int p = i >> 6, q = (i >> 3) & 7, m = i & 7;
    const int l = p >> 2, pp = p & 3;
    const int qg = qBase + q;
    const float2 of = *(const float2*)&coords[(size_t)qg * 256 + ((m * 4 + l) * 4 + pp) * 2];
    const float aw = s_attn[i];
    const int W = 128 >> l;
    const int st = (l == 0) ? 0 : (l == 1) ? 16384 : (l == 2) ? 20480 : 21504;
    const float xf = floorf(of.x), yf = floorf(of.y);
    const int x0 = (int)xf, y0 = (int)yf;
    const float wx = of.x - xf, wy = of.y - yf;
    uint4 rec;
    unsigned* rp = &rec.x;
#pragma unroll
    for (int c = 0; c < 4; ++c) {
      const int dx = c & 1, dy = c >> 1;
      const int xi = x0 + dx, yi = y0 + dy;
      const bool valid = (xi >= 0) & (xi < W) & (yi >= 0) & (yi < W);
      const float w = (dx ? wx : 1.f - wx) * (dy ? wy : 1.f - wy) * aw;
      union { _Float16 h; unsigned short s; } pk;
      pk.h = (_Float16)w;
      const unsigned idx = (unsigned)(st + yi * W + xi);
      rp[c] = valid ? (idx | ((unsigned)pk.s << 16)) : 0u;
    }
    *(uint4*)&s_pair[i * 4] = rec;
  }
  __syncthreads();

  const int wave = tid >> 6, lane = tid & 63;
  const int qloc = wave * 2 + (lane >> 5);
  const int sub = lane & 31, m = sub >> 2, j = sub & 3;
  const int qg = qBase + qloc;
  const int n = (qg >= LEN_IN) ? 1 : 0;
  const char* base = (const char*)value16 + (size_t)(n * 8 + m) * LEN_IN * 64 + j * 16;
  const int lb = qloc * 8 + m;

  float acc8[8] = {0.f, 0.f, 0.f, 0.f, 0.f, 0.f, 0.f, 0.f};
#pragma unroll 4
  for (int p = 0; p < 16; ++p) {
    const uint4 u4 = *(const uint4*)&s_pair[(p * 64 + lb) * 4];
    const unsigned uu[4] = {u4.x, u4.y, u4.z, u4.w};
#pragma unroll
    for (int c = 0; c < 4; ++c) {
      const unsigned u = uu[c];
      union { unsigned short s; _Float16 h; } pk;
      pk.s = (unsigned short)(u >> 16);
      const float w = (float)pk.h;
      const hv8 v = *(const hv8*)(base + (size_t)(u & 32767u) * 64);
#pragma unroll
      for (int e = 0; e < 8; ++e) acc8[e] = fmaf(w, (float)v[e], acc8[e]);
    }
  }

  hv8 o;
#pragma unroll
  for (int e = 0; e < 8; ++e) o[e] = (_Float16)acc8[e];
  *(hv8*)&outp16[(size_t)qg * 256 + m * 32 + j * 8] = o;
}

// ---------------------------------------------------------------------------
extern "C" void kernel_launch(void* const* d_in, const int* in_sizes, int n_in,
                              void* d_out, int out_size, void* d_ws, size_t ws_size,
                              hipStream_t stream) {
  const float* query   = (const float*)d_in[0];
  const float* refpts  = (const float*)d_in[1];
  const float* flatten = (const float*)d_in[2];
  const float* Wv   = (const float*)d_in[5];
  const float* bv   = (const float*)d_in[6];
  const float* Woff = (const float*)d_in[7];
  const float* boff = (const float*)d_in[8];
  const float* Wa   = (const float*)d_in[9];
  const float* ba   = (const float*)d_in[10];
  const float* Wo   = (const float*)d_in[11];
  const float* bo   = (const float*)d_in[12];
  float* out = (float*)d_out;

  // Workspace (~101 MB): value16 | coords | logits16 | outp16 | weights
  const size_t NE = (size_t)MROWS * 256;            // 11,141,120
  _Float16* value16  = (_Float16*)d_ws;             // NE halves (head planes)
  float*    coords   = (float*)(value16 + NE);      // NE floats
  _Float16* logits16 = (_Float16*)(coords + NE);    // NE/2 halves
  _Float16* outp16   = logits16 + NE / 2;           // NE halves
  _Float16* WvT      = outp16 + NE;                 // 256*256
  _Float16* WoffT2   = WvT + 256 * 256;             // 512*256 (hi|lo)
  _Float16* WaT      = WoffT2 + 512 * 256;          // 128*256
  _Float16* WoT      = WaT + 128 * 256;             // 256*256

  const dim3 blk(256);
  const int mtiles = MROWS / 64;   // 680

  cvt_weights<<<dim3(56), blk, 0, stream>>>(Wv, Woff, Wa, Wo, WvT, WoffT2, WaT, WoT);

  // value = f16(flatten @ Wv + bv) -> head planes
  gemm_pipe<256, 1, 2><<<dim3(mtiles), blk, 0, stream>>>(flatten, WvT, bv, value16);
  // coords = (query @ Woff + boff + ref) * W - 0.5  (f16-split, fp32 out)
  gemm_offs_pipe<<<dim3(mtiles), blk, 0, stream>>>(query, WoffT2, boff, refpts, coords);
  // logits = f16(query @ Wa + ba)
  gemm_pipe<128, 1, 1><<<dim3(mtiles), blk, 0, stream>>>(query, WaT, ba, logits16);
  // sampling -> out_pre (f16)
  sample_kernel<<<dim3(MROWS / 8), blk, 0, stream>>>(value16, coords, logits16, outp16);
  // out = out_pre @ Wo + bo (fp32 to d_out)
  gemm_pipe<256, 0, 0><<<dim3(mtiles), blk, 0, stream>>>(outp16, WoT, bo, out);
}

// Round 8
// 283.765 us; speedup vs baseline: 1.3353x; 1.0398x over previous
//
#include <hip/hip_runtime.h>
#include <cstdint>
#include <cstddef>

// Static problem geometry
#define LEN_IN  21760
#define BATCH   2
#define MROWS   (BATCH * LEN_IN)   // 43520 = 64 * 680
// Levels: (128,128),(64,64),(32,32),(16,16); starts 0,16384,20480,21504

typedef _Float16 hv8 __attribute__((ext_vector_type(8)));   // 8 f16
typedef float    fv4 __attribute__((ext_vector_type(4)));

#define WAIT_LGKM0() __builtin_amdgcn_s_waitcnt(0xC07F)   // lgkmcnt(0) only
#define RAW_BARRIER() __builtin_amdgcn_s_barrier()

// ---------------------------------------------------------------------------
// Weight prep: coalesced 64x64 LDS transpose. K-major [K][N] -> [N][K] f16.
// Woff -> f16-split: rows [0,256) = hi, [256,512) = lo residual.
// ---------------------------------------------------------------------------
__global__ __launch_bounds__(256) void cvt_weights(
    const float* __restrict__ Wv, const float* __restrict__ Woff,
    const float* __restrict__ Wa, const float* __restrict__ Wo,
    _Float16* __restrict__ WvT, _Float16* __restrict__ WoffT2,
    _Float16* __restrict__ WaT, _Float16* __restrict__ WoT)
{
  __shared__ float t[64][65];
  const int id = blockIdx.x, tid = threadIdx.x;
  const int c = tid & 63, r4 = tid >> 6;

  const float* src; _Float16* dst; int N; bool split = false; int nt, kt;
  if (id < 16)      { src = Wv;   dst = WvT;    N = 256; nt = id & 3;        kt = id >> 2; }
  else if (id < 32) { src = Woff; dst = WoffT2; N = 256; nt = (id - 16) & 3; kt = (id - 16) >> 2; split = true; }
  else if (id < 40) { src = Wa;   dst = WaT;    N = 128; nt = (id - 32) & 1; kt = (id - 32) >> 1; }
  else              { src = Wo;   dst = WoT;    N = 256; nt = (id - 40) & 3; kt = (id - 40) >> 2; }
  const int nb = nt * 64, kb = kt * 64;

#pragma unroll
  for (int rr = 0; rr < 16; ++rr) {
    const int r = rr * 4 + r4;
    t[r][c] = src[(size_t)(kb + r) * N + nb + c];
  }
  __syncthreads();
#pragma unroll
  for (int rr = 0; rr < 16; ++rr) {
    const int r = rr * 4 + r4;
    const float v = t[c][r];
    const _Float16 h = (_Float16)v;
    dst[(size_t)(nb + r) * 256 + kb + c] = h;
    if (split)
      dst[(size_t)(256 + nb + r) * 256 + kb + c] = (_Float16)(v - (float)h);
  }
}

// ---------------------------------------------------------------------------
// Pipelined f16 MFMA GEMM, 64 x 128 tile, 256 thr = 4 waves (cols 32 each).
// Register pipelines: A 3-deep (HBM, ~3-iter slack), B 2-deep (L2, ~2-iter).
// CRITICAL: loads issued in NEED ORDER (B(it+2) before A(it+3)) so in-order
// vmcnt retirement never drains young A loads.
// LDS double-buffered; ONE raw barrier per iter, lgkmcnt(0)-only wait.
// NTOT: full output width. AF32: A fp32 (cvt in regs) else f16.
// OUTMODE 0: fp32 row-major; 1: f16 row-major; 2: f16 head planes.
// ---------------------------------------------------------------------------
template<int NTOT, int AF32, int OUTMODE>
__global__ __launch_bounds__(256) void gemm_pipe(
    const void* __restrict__ Ap, const _Float16* __restrict__ Bt,
    const float* __restrict__ bias, void* __restrict__ Cout)
{
  __shared__ _Float16 As[2][64 * 40];
  __shared__ _Float16 Bs[2][128 * 40];

  const int tid = threadIdx.x, lane = tid & 63, wave = tid >> 6;
  const int l15 = lane & 15, quad = lane >> 4;
  const int wc = wave * 32;
  const int rowBase = blockIdx.x * 64;
  const int colBase = blockIdx.y * 128;
  const int rs = tid >> 2, ks = (tid & 3) * 8;

  const float*    A32 = (const float*)Ap;
  const _Float16* A16 = (const _Float16*)Ap;

  float4 pa[3][2]; hv8 pa16[3]; hv8 pb[2][2];

  auto issueA = [&](int it) {
    const int k0 = it * 32, s = it % 3;
    if constexpr (AF32) {
      pa[s][0] = *(const float4*)&A32[(size_t)(rowBase + rs) * 256 + k0 + ks];
      pa[s][1] = *(const float4*)&A32[(size_t)(rowBase + rs) * 256 + k0 + ks + 4];
    } else {
      pa16[s] = *(const hv8*)&A16[(size_t)(rowBase + rs) * 256 + k0 + ks];
    }
  };
  auto issueB = [&](int it) {
    const int k0 = it * 32, s = it & 1;
#pragma unroll
    for (int p = 0; p < 2; ++p)
      pb[s][p] = *(const hv8*)&Bt[(size_t)(colBase + p * 64 + rs) * 256 + k0 + ks];
  };

  // Preamble in need order
  issueA(0); issueB(0); issueA(1); issueB(1); issueA(2);

  fv4 acc[4][2] = {};

#pragma unroll
  for (int it = 0; it < 8; ++it) {
    const int sb = it & 1, sa = it % 3;
    if constexpr (AF32) {
      const float4 f0 = pa[sa][0], f1 = pa[sa][1];
      const float fa[8] = {f0.x, f0.y, f0.z, f0.w, f1.x, f1.y, f1.z, f1.w};
      hv8 h;
#pragma unroll
      for (int e = 0; e < 8; ++e) h[e] = (_Float16)fa[e];
      *(hv8*)&As[sb][rs * 40 + ks] = h;
    } else {
      *(hv8*)&As[sb][rs * 40 + ks] = pa16[sa];
    }
#pragma unroll
    for (int p = 0; p < 2; ++p)
      *(hv8*)&Bs[sb][(p * 64 + rs) * 40 + ks] = pb[sb][p];
    if (it + 2 < 8) issueB(it + 2);   // need order: B first,
    if (it + 3 < 8) issueA(it + 3);   // then A
    WAIT_LGKM0();
    RAW_BARRIER();

    hv8 af[4];
#pragma unroll
    for (int i = 0; i < 4; ++i)
      af[i] = *(const hv8*)&As[sb][(i * 16 + l15) * 40 + quad * 8];
#pragma unroll
    for (int j = 0; j < 2; ++j) {
      const hv8 bf = *(const hv8*)&Bs[sb][(wc + j * 16 + l15) * 40 + quad * 8];
#pragma unroll
      for (int i = 0; i < 4; ++i)
        acc[i][j] = __builtin_amdgcn_mfma_f32_16x16x32_f16(af[i], bf, acc[i][j], 0, 0, 0);
    }
    // Double buffer: reads of buf sb complete before next iter's lgkm wait,
    // so writes to buf sb at it+2 are safe with one barrier per iter.
  }

#pragma unroll
  for (int j = 0; j < 2; ++j) {
    const int col = colBase + wc + j * 16 + l15;
    const float bj = bias[col];
#pragma unroll
    for (int i = 0; i < 4; ++i)
#pragma unroll
      for (int rg = 0; rg < 4; ++rg) {
        const int row = rowBase + i * 16 + quad * 4 + rg;
        const float v = acc[i][j][rg] + bj;
        if constexpr (OUTMODE == 0) {
          ((float*)Cout)[(size_t)row * NTOT + col] = v;
        } else if constexpr (OUTMODE == 1) {
          ((_Float16*)Cout)[(size_t)row * NTOT + col] = (_Float16)v;
        } else {
          const int n = (row >= LEN_IN) ? 1 : 0;
          const int pix = row - n * LEN_IN;
          const int m = col >> 5, d = col & 31;
          ((_Float16*)Cout)[((size_t)(n * 8 + m) * LEN_IN + pix) * 32 + d] = (_Float16)v;
        }
      }
  }
}

// ---------------------------------------------------------------------------
// Pipelined offsets GEMM, f16-split A and B (3 MFMAs: hh+hl+lh).
// 64 x 128 coord-cols per block; B2 = [512][256] (hi | lo). Single-buffer
// LDS (30.7 KB), two raw barriers/iter. Same need-order load pipeline.
// Epilogue fuses (acc + boff + ref) * W - 0.5 -> pixel coords fp32.
// ---------------------------------------------------------------------------
__global__ __launch_bounds__(256) void gemm_offs_pipe(
    const float* __restrict__ A, const _Float16* __restrict__ B2,
    const float* __restrict__ boff, const float* __restrict__ refpts,
    float* __restrict__ C)
{
  __shared__ _Float16 Ash[64 * 40], Asl[64 * 40];
  __shared__ _Float16 Bs[256 * 40];   // rows 0-127 hi, 128-255 lo

  const int tid = threadIdx.x, lane = tid & 63, wave = tid >> 6;
  const int l15 = lane & 15, quad = lane >> 4;
  const int wc = wave * 32;
  const int rowBase = blockIdx.x * 64;
  const int colBase = blockIdx.y * 128;
  const int rs = tid >> 2, ks = (tid & 3) * 8;

  float4 pa[3][2]; hv8 pb[2][4];

  auto issueA = [&](int it) {
    const int k0 = it * 32, s = it % 3;
    pa[s][0] = *(const float4*)&A[(size_t)(rowBase + rs) * 256 + k0 + ks];
    pa[s][1] = *(const float4*)&A[(size_t)(rowBase + rs) * 256 + k0 + ks + 4];
  };
  auto issueB = [&](int it) {
    const int k0 = it * 32, s = it & 1;
#pragma unroll
    for (int p = 0; p < 4; ++p) {
      const int grow = (p < 2) ? (colBase + p * 64 + rs)
                               : (256 + colBase + (p - 2) * 64 + rs);
      pb[s][p] = *(const hv8*)&B2[(size_t)grow * 256 + k0 + ks];
    }
  };

  issueA(0); issueB(0); issueA(1); issueB(1); issueA(2);

  fv4 acc[4][2] = {};

#pragma unroll
  for (int it = 0; it < 8; ++it) {
    const int sa = it % 3, s2 = it & 1;
    {
      const float4 f0 = pa[sa][0], f1 = pa[sa][1];
      const float fa[8] = {f0.x, f0.y, f0.z, f0.w, f1.x, f1.y, f1.z, f1.w};
      hv8 hh, ll;
#pragma unroll
      for (int e = 0; e < 8; ++e) {
        hh[e] = (_Float16)fa[e];
        ll[e] = (_Float16)(fa[e] - (float)hh[e]);
      }
      *(hv8*)&Ash[rs * 40 + ks] = hh;
      *(hv8*)&Asl[rs * 40 + ks] = ll;
    }
#pragma unroll
    for (int p = 0; p < 4; ++p)
      *(hv8*)&Bs[(p * 64 + rs) * 40 + ks] = pb[s2][p];
    if (it + 2 < 8) issueB(it + 2);
    if (it + 3 < 8) issueA(it + 3);
    WAIT_LGKM0();
    RAW_BARRIER();

    hv8 ah[4], al[4];
#pragma unroll
    for (int i = 0; i < 4; ++i) {
      ah[i] = *(const hv8*)&Ash[(i * 16 + l15) * 40 + quad * 8];
      al[i] = *(const hv8*)&Asl[(i * 16 + l15) * 40 + quad * 8];
    }
#pragma unroll
    for (int j = 0; j < 2; ++j) {
      const hv8 bh = *(const hv8*)&Bs[(wc + j * 16 + l15) * 40 + quad * 8];
      const hv8 bl = *(const hv8*)&Bs[(128 + wc + j * 16 + l15) * 40 + quad * 8];
#pragma unroll
      for (int i = 0; i < 4; ++i) {
        acc[i][j] = __builtin_amdgcn_mfma_f32_16x16x32_f16(ah[i], bh, acc[i][j], 0, 0, 0);
        acc[i][j] = __builtin_amdgcn_mfma_f32_16x16x32_f16(ah[i], bl, acc[i][j], 0, 0, 0);
        acc[i][j] = __builtin_amdgcn_mfma_f32_16x16x32_f16(al[i], bh, acc[i][j], 0, 0, 0);
      }
    }
    WAIT_LGKM0();   // frag reads done before next iter overwrites (single buf)
    RAW_BARRIER();
  }

  // col c = (((m*4+l)*4+p)*2+xy); write (acc + boff + ref) * W - 0.5
#pragma unroll
  for (int j = 0; j < 2; ++j) {
    const int c = colBase + wc + j * 16 + l15;
    const int xy = c & 1, l = (c >> 3) & 3;
    const float Wl = (float)(128 >> l);
    const float bj = boff[c];
#pragma unroll
    for (int i = 0; i < 4; ++i)
#pragma unroll
      for (int rg = 0; rg < 4; ++rg) {
        const int row = rowBase + i * 16 + quad * 4 + rg;
        const float ref = refpts[(size_t)row * 8 + l * 2 + xy];
        C[(size_t)row * 256 + c] = (acc[i][j][rg] + bj + ref) * Wl - 0.5f;
      }
  }
}

// ---------------------------------------------------------------------------
// Sampler (unchanged: 69.5 us, conflict-free, gather/VALU-bound).
// ---------------------------------------------------------------------------
__global__ __launch_bounds__(256, 6) void sample_kernel(
    const _Float16* __restrict__ value16,  // head planes
    const float* __restrict__ coords,      // (B, LQ, 256) pixel coords
    const _Float16* __restrict__ logits16, // (B, LQ, 128)
    _Float16* __restrict__ outp16)         // (B, LQ, 256)
{
  __shared__ unsigned s_pair[4096];
  __shared__ float    s_attn[1024];

  const int tid = threadIdx.x;
  const int qBase = blockIdx.x * 8;

  if (tid < 64) {   // softmax per (q,m) over 16
    const hv8* lp = (const hv8*)&logits16[(size_t)(qBase + (tid >> 3)) * 128 + (tid & 7) * 16];
    const hv8 w0 = lp[0], w1 = lp[1];
    float w[16];
#pragma unroll
    for (int e = 0; e < 8; ++e) { w[e] = (float)w0[e]; w[8 + e] = (float)w1[e]; }
    float mx = w[0];
#pragma unroll
    for (int i = 1; i < 16; ++i) mx = fmaxf(mx, w[i]);
    float sum = 0.f;
#pragma unroll
    for (int i = 0; i < 16; ++i) { w[i] = expf(w[i] - mx); sum += w[i]; }
    const float inv = 1.f / sum;
#pragma unroll
    for (int p = 0; p < 16; ++p) s_attn[p * 64 + tid] = w[p] * inv;
  }
  __syncthreads();

#pragma unroll
  for (int k = 0; k < 4; ++k) {
    const int i = tid + 256 * k;
    const int p = i >> 6, q = (i >> 3) & 7, m = i & 7;
    const int l = p >> 2, pp = p & 3;
    const int qg = qBase + q;
    const float2 of = *(const float2*)&coords[(size_t)qg * 256 + ((m * 4 + l) * 4 + pp) * 2];
    const float aw = s_attn[i];
    const int W = 128 >> l;
    const int st = (l == 0) ? 0 : (l == 1) ? 16384 : (l == 2) ? 20480 : 21504;
    const float xf = floorf(of.x), yf = floorf(of.y);
    const int x0 = (int)xf, y0 = (int)yf;
    const float wx = of.x - xf, wy = of.y - yf;
    uint4 rec;
    unsigned* rp = &rec.x;
#pragma unroll
    for (int c = 0; c < 4; ++c) {
      const int dx = c & 1, dy = c >> 1;
      const int xi = x0 + dx, yi = y0 + dy;
      const bool valid = (xi >= 0) & (xi < W) & (yi >= 0) & (yi < W);
      const float w = (dx ? wx : 1.f - wx) * (dy ? wy : 1.f - wy) * aw;
      union { _Float16 h; unsigned short s; } pk;
      pk.h = (_Float16)w;
      const unsigned idx = (unsigned)(st + yi * W + xi);
      rp[c] = valid ? (idx | ((unsigned)pk.s << 16)) : 0u;
    }
    *(uint4*)&s_pair[i * 4] = rec;
  }
  __syncthreads();

  const int wave = tid >> 6, lane = tid & 63;
  const int qloc = wave * 2 + (lane >> 5);
  const int sub = lane & 31, m = sub >> 2, j = sub & 3;
  const int qg = qBase + qloc;
  const int n = (qg >= LEN_IN) ? 1 : 0;
  const char* base = (const char*)value16 + (size_t)(n * 8 + m) * LEN_IN * 64 + j * 16;
  const int lb = qloc * 8 + m;

  float acc8[8] = {0.f, 0.f, 0.f, 0.f, 0.f, 0.f, 0.f, 0.f};
#pragma unroll 4
  for (int p = 0; p < 16; ++p) {
    const uint4 u4 = *(const uint4*)&s_pair[(p * 64 + lb) * 4];
    const unsigned uu[4] = {u4.x, u4.y, u4.z, u4.w};
#pragma unroll
    for (int c = 0; c < 4; ++c) {
      const unsigned u = uu[c];
      union { unsigned short s; _Float16 h; } pk;
      pk.s = (unsigned short)(u >> 16);
      const float w = (float)pk.h;
      const hv8 v = *(const hv8*)(base + (size_t)(u & 32767u) * 64);
#pragma unroll
      for (int e = 0; e < 8; ++e) acc8[e] = fmaf(w, (float)v[e], acc8[e]);
    }
  }

  hv8 o;
#pragma unroll
  for (int e = 0; e < 8; ++e) o[e] = (_Float16)acc8[e];
  *(hv8*)&outp16[(size_t)qg * 256 + m * 32 + j * 8] = o;
}

// ---------------------------------------------------------------------------
extern "C" void kernel_launch(void* const* d_in, const int* in_sizes, int n_in,
                              void* d_out, int out_size, void* d_ws, size_t ws_size,
                              hipStream_t stream) {
  const float* query   = (const float*)d_in[0];
  const float* refpts  = (const float*)d_in[1];
  const float* flatten = (const float*)d_in[2];
  const float* Wv   = (const float*)d_in[5];
  const float* bv   = (const float*)d_in[6];
  const float* Woff = (const float*)d_in[7];
  const float* boff = (const float*)d_in[8];
  const float* Wa   = (const float*)d_in[9];
  const float* ba   = (const float*)d_in[10];
  const float* Wo   = (const float*)d_in[11];
  const float* bo   = (const float*)d_in[12];
  float* out = (float*)d_out;

  // Workspace (~101 MB): value16 | coords | logits16 | outp16 | weights
  const size_t NE = (size_t)MROWS * 256;            // 11,141,120
  _Float16* value16  = (_Float16*)d_ws;             // NE halves (head planes)
  float*    coords   = (float*)(value16 + NE);      // NE floats
  _Float16* logits16 = (_Float16*)(coords + NE);    // NE/2 halves
  _Float16* outp16   = logits16 + NE / 2;           // NE halves
  _Float16* WvT      = outp16 + NE;                 // 256*256
  _Float16* WoffT2   = WvT + 256 * 256;             // 512*256 (hi|lo)
  _Float16* WaT      = WoffT2 + 512 * 256;          // 128*256
  _Float16* WoT      = WaT + 128 * 256;             // 256*256

  const dim3 blk(256);
  const int mtiles = MROWS / 64;   // 680

  cvt_weights<<<dim3(56), blk, 0, stream>>>(Wv, Woff, Wa, Wo, WvT, WoffT2, WaT, WoT);

  // value = f16(flatten @ Wv + bv) -> head planes
  gemm_pipe<256, 1, 2><<<dim3(mtiles, 2), blk, 0, stream>>>(flatten, WvT, bv, value16);
  // coords = (query @ Woff + boff + ref) * W - 0.5  (f16-split, fp32 out)
  gemm_offs_pipe<<<dim3(mtiles, 2), blk, 0, stream>>>(query, WoffT2, boff, refpts, coords);
  // logits = f16(query @ Wa + ba)
  gemm_pipe<128, 1, 1><<<dim3(mtiles, 1), blk, 0, stream>>>(query, WaT, ba, logits16);
  // sampling -> out_pre (f16)
  sample_kernel<<<dim3(MROWS / 8), blk, 0, stream>>>(value16, coords, logits16, outp16);
  // out = out_pre @ Wo + bo (fp32 to d_out)
  gemm_pipe<256, 0, 0><<<dim3(mtiles, 2), blk, 0, stream>>>(outp16, WoT, bo, out);
}